// Round 12
// baseline (117.467 us; speedup 1.0000x reference)
//
#include <hip/hip_runtime.h>

// Problem constants
#define NB 4
#define NH 16
#define RR 512
#define CC 512
#define EMB 256
#define SD 16   // qkv dim per head
#define MH 16   // mlp hidden

typedef __attribute__((ext_vector_type(4))) float f32x4;
typedef __fp16 half2v __attribute__((ext_vector_type(2)));
typedef __fp16 half4v __attribute__((ext_vector_type(4)));
typedef __fp16 half8v __attribute__((ext_vector_type(8)));

union H8 { half8v v; half2v h[4]; __fp16 e[8]; };
union H4 { half4v v; half2v h[2]; __fp16 e[4]; };

// Guaranteed VOP3P packed f16 ops (R7-proven correct). Builtin fdot2 is used
// for dot contractions (R7-proven; raw-asm v_dot2 mis-encodes -> R8 failure).
__device__ __forceinline__ unsigned pk_fma(unsigned a, unsigned b, unsigned c) {
  unsigned d;
  asm("v_pk_fma_f16 %0, %1, %2, %3" : "=v"(d) : "v"(a), "v"(b), "v"(c));
  return d;
}
__device__ __forceinline__ unsigned pk_max(unsigned a, unsigned b) {
  unsigned d;
  asm("v_pk_max_f16 %0, %1, %2" : "=v"(d) : "v"(a), "v"(b));
  return d;
}
__device__ __forceinline__ half2v bch(unsigned u) { return __builtin_bit_cast(half2v, u); }
__device__ __forceinline__ unsigned bcu(half2v h) { return __builtin_bit_cast(unsigned, h); }

// ---------------------------------------------------------------------------
// Kernel 0: (a) W[e][n] (256x256 fp32) -> WT[n][e] f16 (blocks 0..191);
//           (b) block 192: pack per-head MLP weights into WPK[h][40] dwords
//               (wa2[0..7], wc2[8..15], wd2[16..23], we2[24..31], wb2 bits[32])
//               so attn blocks do ~5 s_loads instead of ~100 dwords + 64 cvts.
// ---------------------------------------------------------------------------
__global__ __launch_bounds__(256) void prep_w(
    const float* __restrict__ Wq, const float* __restrict__ Wk,
    const float* __restrict__ Wv,
    const float* __restrict__ m1w, const float* __restrict__ m1b,
    const float* __restrict__ m2w, const float* __restrict__ m2b,
    __fp16* __restrict__ WT, unsigned* __restrict__ wpk) {
  int bi = blockIdx.x;
  if (bi == 192) {                       // MLP weight packing: 16 active lanes
    int t = threadIdx.x;
    if (t < NH) {
      unsigned base = t * 40;
#pragma unroll
      for (int mp = 0; mp < 8; ++mp) {
        wpk[base + mp] =
            bcu(half2v{(__fp16)(m1w[(t * 2 + 0) * MH + 2 * mp] * 0.25f),
                       (__fp16)(m1w[(t * 2 + 0) * MH + 2 * mp + 1] * 0.25f)});
        wpk[base + 8 + mp] =
            bcu(half2v{(__fp16)m1w[(t * 2 + 1) * MH + 2 * mp],
                       (__fp16)m1w[(t * 2 + 1) * MH + 2 * mp + 1]});
        wpk[base + 16 + mp] =
            bcu(half2v{(__fp16)m1b[t * MH + 2 * mp],
                       (__fp16)m1b[t * MH + 2 * mp + 1]});
        wpk[base + 24 + mp] =
            bcu(half2v{(__fp16)m2w[t * MH + 2 * mp],
                       (__fp16)m2w[t * MH + 2 * mp + 1]});
      }
      wpk[base + 32] = __builtin_bit_cast(unsigned, m2b[t]);
    }
    return;
  }
  int mat = bi >> 6, chunk = bi & 63;
  const float* src = (mat == 0) ? Wq : (mat == 1) ? Wk : Wv;
  __fp16* dst = WT + mat * (EMB * EMB);
  int t = threadIdx.x;
  int n = chunk * 4 + (t >> 6);
  int e0 = (t & 63) * 4;
  H4 v;
#pragma unroll
  for (int j = 0; j < 4; ++j) v.e[j] = (__fp16)src[(e0 + j) * EMB + n];
  *(half4v*)(dst + n * EMB + e0) = v.v;
}

// ---------------------------------------------------------------------------
// Kernel 1: projections (f16 MFMA). Wave converts 16 X-rows to f16 once,
// reuses across 4 heads. 1536 waves -> 384 blocks x 256 thr.
//   mat 0: Q[b,h,r,s]; mat 1: K[b,h,c,s]; mat 2: VT[b,h,s,c].
// ---------------------------------------------------------------------------
__global__ __launch_bounds__(256) void proj_kernel(
    const float* __restrict__ rowe, const float* __restrict__ cole,
    const __fp16* __restrict__ WT,
    __fp16* __restrict__ Q, __fp16* __restrict__ K,
    __fp16* __restrict__ VT) {
  int tid = threadIdx.x;
  int wid = tid >> 6, lane = tid & 63, l15 = lane & 15, quad = lane >> 4;
  int wt = blockIdx.x * 4 + wid;        // 0..1535
  int mat = wt >> 9;                    // 0=Q 1=K 2=V
  int t = wt & 511;
  int rt = t >> 2, ng = t & 3;          // rt 0..127, head group 0..3
  const float* X = (mat == 0) ? rowe : cole;
  const __fp16* Wm = WT + mat * (EMB * EMB);
  const float* xrow = X + (size_t)(rt * 16 + l15) * EMB + quad * 8;

  half8v xf[8];
#pragma unroll
  for (int e = 0; e < 8; ++e) {
    f32x4 b0 = *(const f32x4*)(xrow + e * 32);
    f32x4 b1 = *(const f32x4*)(xrow + e * 32 + 4);
    H8 x;
    x.h[0] = __builtin_amdgcn_cvt_pkrtz(b0[0], b0[1]);
    x.h[1] = __builtin_amdgcn_cvt_pkrtz(b0[2], b0[3]);
    x.h[2] = __builtin_amdgcn_cvt_pkrtz(b1[0], b1[1]);
    x.h[3] = __builtin_amdgcn_cvt_pkrtz(b1[2], b1[3]);
    xf[e] = x.v;
  }
  int row = rt * 16 + l15;
  int b = row >> 9, loc = row & 511;
#pragma unroll
  for (int hh = 0; hh < 4; ++hh) {
    int nt = ng * 4 + hh;
    const half8v* ap = (const half8v*)(Wm + (nt * 16 + l15) * EMB + quad * 8);
    f32x4 acc = {0.f, 0.f, 0.f, 0.f};
#pragma unroll
    for (int e = 0; e < 8; ++e)
      acc = __builtin_amdgcn_mfma_f32_16x16x32_f16(ap[e * 4], xf[e], acc, 0, 0, 0);
    if (mat < 2) {
      H4 pk;
      pk.h[0] = __builtin_amdgcn_cvt_pkrtz(acc[0], acc[1]);
      pk.h[1] = __builtin_amdgcn_cvt_pkrtz(acc[2], acc[3]);
      __fp16* dst = ((mat == 0) ? Q : K) +
          ((size_t)((b * NH + nt) * 512 + loc) * SD + quad * 4);
      *(half4v*)dst = pk.v;
    } else {
#pragma unroll
      for (int i = 0; i < 4; ++i)
        VT[(size_t)((b * NH + nt) * SD + quad * 4 + i) * CC + loc] = (__fp16)acc[i];
    }
  }
}

// ---------------------------------------------------------------------------
// Kernel 2: fused mixed-score attention, single-phase, register-resident P,
// PRE-PACKED weights (the R12 change: block prologue = ~5 s_loads, no cvts).
// grid (32 rb, 16 h, 4 b) x 256 thr. Block = 1 row-tile (16 r) x 4 c-chunks.
// Layout identity: QK-MFMA C-layout (r=lane&15, c=quad*4+i) == A-operand
// layout of v_mfma_f32_16x16x16f16 -> P feeds P.V MFMA from registers.
// Per iter: MFMA S^T -> packed-f16 MLP -> exp2 (no-max softmax, R9-proven)
//           -> pack half4 -> lsum fdot2 -> mfma_16x16x16(P, VTfrag, o).
// Merge: plain sums across 4 waves via 3.3 KB LDS, one barrier.
// ---------------------------------------------------------------------------
__global__ __launch_bounds__(256, 4) void attn_kernel(
    const __fp16* __restrict__ Q, const __fp16* __restrict__ K,
    const __fp16* __restrict__ VT, const float* __restrict__ cost,
    const unsigned* __restrict__ wpk, float* __restrict__ out) {
  __shared__ float Osh[3][256];                        // waves 1..3 partial O
  __shared__ float Lsh[4][16];                         // [wave][row] partial l
  int tid = threadIdx.x;
  int wid = tid >> 6, lane = tid & 63, l15 = lane & 15, quad = lane >> 4;
  int rb = blockIdx.x, h = blockIdx.y, b = blockIdx.z;
  int bh = b * NH + h;
  int r0 = rb * 16;
  int cbase = wid * 128;

  // pre-packed per-head MLP weights: 33 uniform dwords (s_load_dwordx8 x4 + 1)
  const unsigned* wp = wpk + h * 40;
  unsigned wa2[8], wc2[8], wd2[8], we2[8];
#pragma unroll
  for (int mp = 0; mp < 8; ++mp) {
    wa2[mp] = wp[mp];
    wc2[mp] = wp[8 + mp];
    wd2[mp] = wp[16 + mp];
    we2[mp] = wp[24 + mp];
  }
  float wb2 = __builtin_bit_cast(float, wp[32]);
  const half2v one2 = {(__fp16)1.f, (__fp16)1.f};

  // loop-invariant Q fragment (B-operand): zero for k>=16 -> kills junk K k>=16
  half8v qf = {0, 0, 0, 0, 0, 0, 0, 0};
  const __fp16* Qb = Q + (size_t)bh * RR * SD;
  if (quad < 2) qf = *(const half8v*)(Qb + (r0 + l15) * SD + quad * 8);

  const __fp16* Kb = K + ((size_t)bh * CC + cbase) * SD;
  const float* crow = cost + ((size_t)b * RR + r0 + l15) * CC + cbase;
  // V fragment rows for the P.V MFMA: B[k=c][n=s] -> lane l15 = s
  const __fp16* vrow = VT + ((size_t)bh * SD + l15) * CC + cbase;

  // ---- batch-preload all cost (8 x 16B, one latency exposure) ----
  f32x4 cf[8];
#pragma unroll
  for (int it = 0; it < 8; ++it)
    cf[it] = *(const f32x4*)(crow + it * 16 + quad * 4);

  // ---- single-phase loop: scores + MLP + exp + P.V (K depth-2 prefetch) ----
  const float L2E = 1.44269504088896f;
  float lsum = 0.f;
  f32x4 o = {0.f, 0.f, 0.f, 0.f};
  half8v kf0 = *(const half8v*)(Kb + l15 * SD + quad * 8);        // junk k>=16 ok
  half8v kf1 = *(const half8v*)(Kb + (16 + l15) * SD + quad * 8);
#pragma unroll
  for (int it = 0; it < 8; ++it) {
    int itn = (it + 2) & 7;                    // wrap: redundant reload, harmless
    half8v kf_n = *(const half8v*)(Kb + (itn * 16 + l15) * SD + quad * 8);
    half4v vf = *(const half4v*)(vrow + it * 16 + quad * 4);

    f32x4 acc = {0.f, 0.f, 0.f, 0.f};
    acc = __builtin_amdgcn_mfma_f32_16x16x32_f16(kf0, qf, acc, 0, 0, 0);
    // lane: r = r0+l15 (fixed), local c = it*16 + 4*quad + i
    float pv[4];
#pragma unroll
    for (int i = 0; i < 4; ++i) {
      unsigned x2 = bcu(__builtin_amdgcn_cvt_pkrtz(acc[i], acc[i]));
      unsigned c2 = bcu(__builtin_amdgcn_cvt_pkrtz(cf[it][i], cf[it][i]));
      float s = wb2;
#pragma unroll
      for (int mp = 0; mp < 8; ++mp) {
        unsigned t1 = pk_fma(wc2[mp], c2, wd2[mp]);
        t1 = pk_fma(wa2[mp], x2, t1);
        t1 = pk_max(t1, 0u);
        s = __builtin_amdgcn_fdot2(bch(we2[mp]), bch(t1), s, false);
      }
      pv[i] = __builtin_amdgcn_exp2f(fmaf(s, L2E, -6.f));  // scaled exp, 2^-6
    }
    H4 pk;
    pk.h[0] = __builtin_amdgcn_cvt_pkrtz(pv[0], pv[1]);
    pk.h[1] = __builtin_amdgcn_cvt_pkrtz(pv[2], pv[3]);
    lsum = __builtin_amdgcn_fdot2(pk.h[0], one2, lsum, false);
    lsum = __builtin_amdgcn_fdot2(pk.h[1], one2, lsum, false);
    // P (A-layout m=r,k=c) x V^T fragment (B-layout k=c,n=s) -> O^T in C-layout
    o = __builtin_amdgcn_mfma_f32_16x16x16f16(pk.v, vf, o, 0, 0, 0);
    kf0 = kf1; kf1 = kf_n;
  }
  lsum += __shfl_xor(lsum, 16);
  lsum += __shfl_xor(lsum, 32);               // per-row (l15) partial l

  // ---- merge the four c-chunks: plain sums (no-max softmax), 1 barrier ----
  if (quad == 0) Lsh[wid][l15] = lsum;
  if (wid != 0) {
#pragma unroll
    for (int i = 0; i < 4; ++i) Osh[wid - 1][(quad * 4 + i) * 16 + l15] = o[i];
  }
  __syncthreads();
  if (wid == 0) {
#pragma unroll
    for (int i = 0; i < 4; ++i) {
      int r = quad * 4 + i;
      float l = Lsh[0][r] + Lsh[1][r] + Lsh[2][r] + Lsh[3][r];
      float num = o[i] + Osh[0][r * 16 + l15] + Osh[1][r * 16 + l15] +
                  Osh[2][r * 16 + l15];
      out[((size_t)b * RR + r0 + r) * (NH * SD) + h * SD + l15] = num / l;
    }
  }
}

// ---------------------------------------------------------------------------
extern "C" void kernel_launch(void* const* d_in, const int* in_sizes, int n_in,
                              void* d_out, int out_size, void* d_ws, size_t ws_size,
                              hipStream_t stream) {
  const float* rowe = (const float*)d_in[0];
  const float* cole = (const float*)d_in[1];
  const float* cost = (const float*)d_in[2];
  const float* Wq   = (const float*)d_in[3];
  const float* Wk   = (const float*)d_in[4];
  const float* Wv   = (const float*)d_in[5];
  const float* m1w  = (const float*)d_in[6];
  const float* m1b  = (const float*)d_in[7];
  const float* m2w  = (const float*)d_in[8];
  const float* m2b  = (const float*)d_in[9];
  float* outp = (float*)d_out;

  // workspace layout (f16 elements):
  //   Q  [4,16,512,16]  @ 0        (524288)
  //   K  [4,16,512,16]  @ 524288   (524288)
  //   VT [4,16,16,512]  @ 1048576  (524288)
  //   WT [3,256,256]    @ 1572864  (196608)
  //   WPK[16][40] dwords @ f16-offset 1769472 (2560 B)  -> ~3.54 MB total
  __fp16* ws = (__fp16*)d_ws;
  __fp16* Qw  = ws;
  __fp16* Kw  = ws + 524288;
  __fp16* VTw = ws + 1048576;
  __fp16* WTw = ws + 1572864;
  unsigned* WPKw = (unsigned*)(ws + 1769472);   // 16B-aligned

  prep_w<<<dim3(193, 1, 1), 256, 0, stream>>>(Wq, Wk, Wv, m1w, m1b, m2w, m2b,
                                              WTw, WPKw);
  proj_kernel<<<dim3(384, 1, 1), 256, 0, stream>>>(rowe, cole, WTw, Qw, Kw, VTw);
  attn_kernel<<<dim3(32, NH, NB), 256, 0, stream>>>(Qw, Kw, VTw, cost,
                                                    WPKw, outp);
}

// Round 13
// 117.244 us; speedup vs baseline: 1.0019x; 1.0019x over previous
//
#include <hip/hip_runtime.h>

// Problem constants
#define NB 4
#define NH 16
#define RR 512
#define CC 512
#define EMB 256
#define SD 16   // qkv dim per head
#define MH 16   // mlp hidden

typedef __attribute__((ext_vector_type(4))) float f32x4;
typedef __fp16 half2v __attribute__((ext_vector_type(2)));
typedef __fp16 half4v __attribute__((ext_vector_type(4)));
typedef __fp16 half8v __attribute__((ext_vector_type(8)));

union H8 { half8v v; half2v h[4]; __fp16 e[8]; };
union H4 { half4v v; half2v h[2]; __fp16 e[4]; };

// Guaranteed VOP3P packed f16 ops (R7-proven correct). Builtin fdot2 is used
// for dot contractions (R7-proven; raw-asm v_dot2 mis-encodes -> R8 failure).
__device__ __forceinline__ unsigned pk_fma(unsigned a, unsigned b, unsigned c) {
  unsigned d;
  asm("v_pk_fma_f16 %0, %1, %2, %3" : "=v"(d) : "v"(a), "v"(b), "v"(c));
  return d;
}
__device__ __forceinline__ unsigned pk_max(unsigned a, unsigned b) {
  unsigned d;
  asm("v_pk_max_f16 %0, %1, %2" : "=v"(d) : "v"(a), "v"(b));
  return d;
}
__device__ __forceinline__ half2v bch(unsigned u) { return __builtin_bit_cast(half2v, u); }
__device__ __forceinline__ unsigned bcu(half2v h) { return __builtin_bit_cast(unsigned, h); }

// ---------------------------------------------------------------------------
// Kernel 0: (a) W[e][n] (256x256 fp32) -> WT[n][e] f16 (blocks 0..191);
//           (b) block 192: pack per-head MLP weights into WPK[h][40] dwords.
// ---------------------------------------------------------------------------
__global__ __launch_bounds__(256) void prep_w(
    const float* __restrict__ Wq, const float* __restrict__ Wk,
    const float* __restrict__ Wv,
    const float* __restrict__ m1w, const float* __restrict__ m1b,
    const float* __restrict__ m2w, const float* __restrict__ m2b,
    __fp16* __restrict__ WT, unsigned* __restrict__ wpk) {
  int bi = blockIdx.x;
  if (bi == 192) {                       // MLP weight packing: 16 active lanes
    int t = threadIdx.x;
    if (t < NH) {
      unsigned base = t * 40;
#pragma unroll
      for (int mp = 0; mp < 8; ++mp) {
        wpk[base + mp] =
            bcu(half2v{(__fp16)(m1w[(t * 2 + 0) * MH + 2 * mp] * 0.25f),
                       (__fp16)(m1w[(t * 2 + 0) * MH + 2 * mp + 1] * 0.25f)});
        wpk[base + 8 + mp] =
            bcu(half2v{(__fp16)m1w[(t * 2 + 1) * MH + 2 * mp],
                       (__fp16)m1w[(t * 2 + 1) * MH + 2 * mp + 1]});
        wpk[base + 16 + mp] =
            bcu(half2v{(__fp16)m1b[t * MH + 2 * mp],
                       (__fp16)m1b[t * MH + 2 * mp + 1]});
        wpk[base + 24 + mp] =
            bcu(half2v{(__fp16)m2w[t * MH + 2 * mp],
                       (__fp16)m2w[t * MH + 2 * mp + 1]});
      }
      wpk[base + 32] = __builtin_bit_cast(unsigned, m2b[t]);
    }
    return;
  }
  int mat = bi >> 6, chunk = bi & 63;
  const float* src = (mat == 0) ? Wq : (mat == 1) ? Wk : Wv;
  __fp16* dst = WT + mat * (EMB * EMB);
  int t = threadIdx.x;
  int n = chunk * 4 + (t >> 6);
  int e0 = (t & 63) * 4;
  H4 v;
#pragma unroll
  for (int j = 0; j < 4; ++j) v.e[j] = (__fp16)src[(e0 + j) * EMB + n];
  *(half4v*)(dst + n * EMB + e0) = v.v;
}

// ---------------------------------------------------------------------------
// Kernel 1: projections (f16 MFMA). Wave converts 16 X-rows to f16 once,
// reuses across 4 heads. 1536 waves -> 384 blocks x 256 thr.
//   mat 0: Q[b,h,r,s]; mat 1: K[b,h,c,s]; mat 2: VT[b,h,s,c].
// ---------------------------------------------------------------------------
__global__ __launch_bounds__(256) void proj_kernel(
    const float* __restrict__ rowe, const float* __restrict__ cole,
    const __fp16* __restrict__ WT,
    __fp16* __restrict__ Q, __fp16* __restrict__ K,
    __fp16* __restrict__ VT) {
  int tid = threadIdx.x;
  int wid = tid >> 6, lane = tid & 63, l15 = lane & 15, quad = lane >> 4;
  int wt = blockIdx.x * 4 + wid;        // 0..1535
  int mat = wt >> 9;                    // 0=Q 1=K 2=V
  int t = wt & 511;
  int rt = t >> 2, ng = t & 3;          // rt 0..127, head group 0..3
  const float* X = (mat == 0) ? rowe : cole;
  const __fp16* Wm = WT + mat * (EMB * EMB);
  const float* xrow = X + (size_t)(rt * 16 + l15) * EMB + quad * 8;

  half8v xf[8];
#pragma unroll
  for (int e = 0; e < 8; ++e) {
    f32x4 b0 = *(const f32x4*)(xrow + e * 32);
    f32x4 b1 = *(const f32x4*)(xrow + e * 32 + 4);
    H8 x;
    x.h[0] = __builtin_amdgcn_cvt_pkrtz(b0[0], b0[1]);
    x.h[1] = __builtin_amdgcn_cvt_pkrtz(b0[2], b0[3]);
    x.h[2] = __builtin_amdgcn_cvt_pkrtz(b1[0], b1[1]);
    x.h[3] = __builtin_amdgcn_cvt_pkrtz(b1[2], b1[3]);
    xf[e] = x.v;
  }
  int row = rt * 16 + l15;
  int b = row >> 9, loc = row & 511;
#pragma unroll
  for (int hh = 0; hh < 4; ++hh) {
    int nt = ng * 4 + hh;
    const half8v* ap = (const half8v*)(Wm + (nt * 16 + l15) * EMB + quad * 8);
    f32x4 acc = {0.f, 0.f, 0.f, 0.f};
#pragma unroll
    for (int e = 0; e < 8; ++e)
      acc = __builtin_amdgcn_mfma_f32_16x16x32_f16(ap[e * 4], xf[e], acc, 0, 0, 0);
    if (mat < 2) {
      H4 pk;
      pk.h[0] = __builtin_amdgcn_cvt_pkrtz(acc[0], acc[1]);
      pk.h[1] = __builtin_amdgcn_cvt_pkrtz(acc[2], acc[3]);
      __fp16* dst = ((mat == 0) ? Q : K) +
          ((size_t)((b * NH + nt) * 512 + loc) * SD + quad * 4);
      *(half4v*)dst = pk.v;
    } else {
#pragma unroll
      for (int i = 0; i < 4; ++i)
        VT[(size_t)((b * NH + nt) * SD + quad * 4 + i) * CC + loc] = (__fp16)acc[i];
    }
  }
}

// ---------------------------------------------------------------------------
// Kernel 2: fused mixed-score attention, TWO HEADS PER BLOCK (R13 change).
// grid (32 rb, 8 hp, 4 b) = 1024 blocks = exactly 4/CU x 256 CU: ONE resident
// round. cost (head-invariant!) batch-loaded once, reused by both heads ->
// cost L3 traffic halved (64->32 MB/dispatch).
// Per head: single-phase loop (R11 structure): MFMA S^T -> packed-f16 MLP ->
// exp2 (no-max softmax) -> register-direct P -> mfma_16x16x16(P, VT, o).
// Partial O/L per head to LDS regions, ONE barrier, waves 0/1 finalize h0/h1.
// ---------------------------------------------------------------------------
__global__ __launch_bounds__(256, 4) void attn_kernel(
    const __fp16* __restrict__ Q, const __fp16* __restrict__ K,
    const __fp16* __restrict__ VT, const float* __restrict__ cost,
    const unsigned* __restrict__ wpk, float* __restrict__ out) {
  __shared__ float Osh[2][4][256];                     // [head][wave][r*16+s]
  __shared__ float Lsh[2][4][16];                      // [head][wave][row]
  int tid = threadIdx.x;
  int wid = tid >> 6, lane = tid & 63, l15 = lane & 15, quad = lane >> 4;
  int rb = blockIdx.x, hp = blockIdx.y, b = blockIdx.z;
  int h0 = hp * 2;
  int r0 = rb * 16;
  int cbase = wid * 128;
  const float L2E = 1.44269504088896f;
  const half2v one2 = {(__fp16)1.f, (__fp16)1.f};

  // ---- batch-preload all cost (8 x 16B, one latency exposure, shared by
  //      both heads) ----
  const float* crow = cost + ((size_t)b * RR + r0 + l15) * CC + cbase;
  f32x4 cf[8];
#pragma unroll
  for (int it = 0; it < 8; ++it)
    cf[it] = *(const f32x4*)(crow + it * 16 + quad * 4);

#pragma unroll
  for (int hh = 0; hh < 2; ++hh) {
    int h = h0 + hh;
    int bh = b * NH + h;

    // pre-packed per-head MLP weights: 33 uniform dwords (s_loads)
    const unsigned* wp = wpk + h * 40;
    unsigned wa2[8], wc2[8], wd2[8], we2[8];
#pragma unroll
    for (int mp = 0; mp < 8; ++mp) {
      wa2[mp] = wp[mp];
      wc2[mp] = wp[8 + mp];
      wd2[mp] = wp[16 + mp];
      we2[mp] = wp[24 + mp];
    }
    float wb2 = __builtin_bit_cast(float, wp[32]);

    // loop-invariant Q fragment (B-operand): zero k>=16 kills junk K k>=16
    half8v qf = {0, 0, 0, 0, 0, 0, 0, 0};
    const __fp16* Qb = Q + (size_t)bh * RR * SD;
    if (quad < 2) qf = *(const half8v*)(Qb + (r0 + l15) * SD + quad * 8);

    const __fp16* Kb = K + ((size_t)bh * CC + cbase) * SD;
    const __fp16* vrow = VT + ((size_t)bh * SD + l15) * CC + cbase;

    float lsum = 0.f;
    f32x4 o = {0.f, 0.f, 0.f, 0.f};
    half8v kf0 = *(const half8v*)(Kb + l15 * SD + quad * 8);
    half8v kf1 = *(const half8v*)(Kb + (16 + l15) * SD + quad * 8);
#pragma unroll
    for (int it = 0; it < 8; ++it) {
      int itn = (it + 2) & 7;                  // wrap: redundant reload, harmless
      half8v kf_n = *(const half8v*)(Kb + (itn * 16 + l15) * SD + quad * 8);
      half4v vf = *(const half4v*)(vrow + it * 16 + quad * 4);

      f32x4 acc = {0.f, 0.f, 0.f, 0.f};
      acc = __builtin_amdgcn_mfma_f32_16x16x32_f16(kf0, qf, acc, 0, 0, 0);
      // lane: r = r0+l15 (fixed), local c = it*16 + 4*quad + i
      float pv[4];
#pragma unroll
      for (int i = 0; i < 4; ++i) {
        unsigned x2 = bcu(__builtin_amdgcn_cvt_pkrtz(acc[i], acc[i]));
        unsigned c2 = bcu(__builtin_amdgcn_cvt_pkrtz(cf[it][i], cf[it][i]));
        float s = wb2;
#pragma unroll
        for (int mp = 0; mp < 8; ++mp) {
          unsigned t1 = pk_fma(wc2[mp], c2, wd2[mp]);
          t1 = pk_fma(wa2[mp], x2, t1);
          t1 = pk_max(t1, 0u);
          s = __builtin_amdgcn_fdot2(bch(we2[mp]), bch(t1), s, false);
        }
        pv[i] = __builtin_amdgcn_exp2f(fmaf(s, L2E, -6.f));  // scaled exp 2^-6
      }
      H4 pk;
      pk.h[0] = __builtin_amdgcn_cvt_pkrtz(pv[0], pv[1]);
      pk.h[1] = __builtin_amdgcn_cvt_pkrtz(pv[2], pv[3]);
      lsum = __builtin_amdgcn_fdot2(pk.h[0], one2, lsum, false);
      lsum = __builtin_amdgcn_fdot2(pk.h[1], one2, lsum, false);
      // P (A-layout m=r,k=c) x V^T frag (B-layout k=c,n=s) -> O^T in C-layout
      o = __builtin_amdgcn_mfma_f32_16x16x16f16(pk.v, vf, o, 0, 0, 0);
      kf0 = kf1; kf1 = kf_n;
    }
    lsum += __shfl_xor(lsum, 16);
    lsum += __shfl_xor(lsum, 32);             // per-row (l15) partial l

    // stash this head's partials (per-wave region, no races)
    if (quad == 0) Lsh[hh][wid][l15] = lsum;
#pragma unroll
    for (int i = 0; i < 4; ++i) Osh[hh][wid][(quad * 4 + i) * 16 + l15] = o[i];
  }

  __syncthreads();
  // waves 0/1 finalize heads 0/1 (plain sums across the 4 c-chunks)
  if (wid < 2) {
    int h = h0 + wid;
#pragma unroll
    for (int i = 0; i < 4; ++i) {
      int r = quad * 4 + i;
      float l = Lsh[wid][0][r] + Lsh[wid][1][r] + Lsh[wid][2][r] + Lsh[wid][3][r];
      float num = Osh[wid][0][r * 16 + l15] + Osh[wid][1][r * 16 + l15] +
                  Osh[wid][2][r * 16 + l15] + Osh[wid][3][r * 16 + l15];
      out[((size_t)b * RR + r0 + r) * (NH * SD) + h * SD + l15] = num / l;
    }
  }
}

// ---------------------------------------------------------------------------
extern "C" void kernel_launch(void* const* d_in, const int* in_sizes, int n_in,
                              void* d_out, int out_size, void* d_ws, size_t ws_size,
                              hipStream_t stream) {
  const float* rowe = (const float*)d_in[0];
  const float* cole = (const float*)d_in[1];
  const float* cost = (const float*)d_in[2];
  const float* Wq   = (const float*)d_in[3];
  const float* Wk   = (const float*)d_in[4];
  const float* Wv   = (const float*)d_in[5];
  const float* m1w  = (const float*)d_in[6];
  const float* m1b  = (const float*)d_in[7];
  const float* m2w  = (const float*)d_in[8];
  const float* m2b  = (const float*)d_in[9];
  float* outp = (float*)d_out;

  // workspace layout (f16 elements):
  //   Q  [4,16,512,16]  @ 0        (524288)
  //   K  [4,16,512,16]  @ 524288   (524288)
  //   VT [4,16,16,512]  @ 1048576  (524288)
  //   WT [3,256,256]    @ 1572864  (196608)
  //   WPK[16][40] dwords @ f16-offset 1769472 (2560 B)  -> ~3.54 MB total
  __fp16* ws = (__fp16*)d_ws;
  __fp16* Qw  = ws;
  __fp16* Kw  = ws + 524288;
  __fp16* VTw = ws + 1048576;
  __fp16* WTw = ws + 1572864;
  unsigned* WPKw = (unsigned*)(ws + 1769472);   // 16B-aligned

  prep_w<<<dim3(193, 1, 1), 256, 0, stream>>>(Wq, Wk, Wv, m1w, m1b, m2w, m2b,
                                              WTw, WPKw);
  proj_kernel<<<dim3(384, 1, 1), 256, 0, stream>>>(rowe, cole, WTw, Qw, Kw, VTw);
  attn_kernel<<<dim3(32, 8, NB), 256, 0, stream>>>(Qw, Kw, VTw, cost,
                                                   WPKw, outp);
}